// Round 1
// baseline (309.547 us; speedup 1.0000x reference)
//
#include <hip/hip_runtime.h>
#include <hip/hip_bf16.h>

// out[n,o,(h+1)%56,w] = sum_{c,t} x[n,c,h,w+t-1] * W[o,c,t]   (W-pad 1, H-pad 0)
// Implicit GEMM on MFMA 32x32x16_bf16. K = tap*128 + c.
// LDS: x-window transposed; row j <-> sp = s0-2+j (even start -> dwordx2 staging),
// pitch 68 dwords (conflict-free b128 reads). Row 128 = zeros (boundary-kill row:
// kill is an address select, not 8 cndmasks). ST=122 -> 26 blocks, +4% over-read.

#define NB    128
#define CIN   128
#define SP    3136          // 56*56
#define HSP   1568          // SP/2 in float2 units
#define OUTC  32
#define ST    122           // s-cols stored per block (cloc >= 122 computed-garbage)
#define NT    26            // ceil(3136/122)
#define ROWS  128           // data rows j=0..127 <-> sp = s0-2+j
#define ZROW  128           // zero row for boundary kill
#define CP    136           // LDS row pitch in bf16 (68 dwords)
#define THREADS 256

typedef __attribute__((ext_vector_type(8)))  short bf16x8;   // 8 bf16 = 4 VGPRs
typedef __attribute__((ext_vector_type(16))) float f32x16;   // 32x32 accumulator

__device__ __forceinline__ unsigned short f2bf(float f) {    // RNE f32->bf16
    unsigned u = __float_as_uint(f);
    return (unsigned short)((u + 0x7FFFu + ((u >> 16) & 1u)) >> 16);
}

// packed RNE convert: compiler emits v_cvt_pk_bf16_f32 (1 op vs ~10 manual)
__device__ __forceinline__ unsigned cvt2(float a, float b) {
    union { __hip_bfloat162 h; unsigned u; } z;
    z.h = __float22bfloat162_rn(make_float2(a, b));
    return z.u;
}

// A-frag prep: af[ks][lane][8] bf16; frag elem j of lane = A[m=lane&31][k=ks*16+(lane>>5)*8+j]
__global__ void prep_w(const float* __restrict__ w, unsigned short* __restrict__ af) {
    int i = blockIdx.x * 256 + threadIdx.x;            // over 32 o x 384 k
    if (i >= OUTC * 384) return;
    int k = i % 384, o = i / 384;
    int tap = k / 128, c = k % 128;
    int kstep = k >> 4, klocal = k & 15;
    int lane  = ((klocal >> 3) << 5) + o;
    int j     = klocal & 7;
    af[kstep * 512 + lane * 8 + j] = f2bf(w[o * 384 + c * 3 + tap]);
}

__launch_bounds__(THREADS, 4)
__global__ void conv_mfma(const float* __restrict__ x,
                          const unsigned short* __restrict__ af,
                          float* __restrict__ out) {
    __shared__ unsigned short xs[(ROWS + 1) * CP];     // 35,088 B -> 4 blocks/CU

    const int n  = blockIdx.y;
    const int s0 = blockIdx.x * ST;
    const float* __restrict__ xn = x + (size_t)n * (CIN * SP);

    // zero the kill row (c = 0..127)
    if (threadIdx.x < 16) {
        bf16x8 z = {};
        *(bf16x8*)&xs[ZROW * CP + threadIdx.x * 8] = z;
    }

    // ---- stage x[n, :, s0-2 .. s0+125] transposed into LDS as bf16 ----
    // 1024 pair-items = 4/thread; lane-consecutive pairs -> 512 B/instr dwordx2
#pragma unroll
    for (int it = 0; it < 4; ++it) {
        int i  = threadIdx.x + it * THREADS;           // 0..1023
        int p  = i & 63;                               // s-pair -> rows 2p, 2p+1
        int cg = i >> 6;                               // channel group of 8
        int s  = s0 - 2 + 2 * p;                       // even -> 8B-aligned float2
        s = s < 0 ? 0 : (s > SP - 2 ? SP - 2 : s);     // clamped; junk rows masked at use
        const float2* __restrict__ xp =
            (const float2*)xn + (size_t)(cg * 8) * HSP + (s >> 1);
        float2 v0 = xp[0 * HSP], v1 = xp[1 * HSP], v2 = xp[2 * HSP], v3 = xp[3 * HSP];
        float2 v4 = xp[4 * HSP], v5 = xp[5 * HSP], v6 = xp[6 * HSP], v7 = xp[7 * HSP];
        union { unsigned u[4]; bf16x8 v; } r0, r1;
        r0.u[0] = cvt2(v0.x, v1.x); r0.u[1] = cvt2(v2.x, v3.x);
        r0.u[2] = cvt2(v4.x, v5.x); r0.u[3] = cvt2(v6.x, v7.x);
        r1.u[0] = cvt2(v0.y, v1.y); r1.u[1] = cvt2(v2.y, v3.y);
        r1.u[2] = cvt2(v4.y, v5.y); r1.u[3] = cvt2(v6.y, v7.y);
        *(bf16x8*)&xs[(2 * p)     * CP + cg * 8] = r0.v;
        *(bf16x8*)&xs[(2 * p + 1) * CP + cg * 8] = r1.v;
    }
    __syncthreads();

    const int lane = threadIdx.x & 63;
    const int wid  = threadIdx.x >> 6;                 // wave -> 32-col chunk
    const int cloc = wid * 32 + (lane & 31);           // local column (>=122 garbage)
    const int col  = s0 + cloc;                        // global s
    const int wpos = col % 56;
    const int half = lane >> 5;

    f32x16 acc;
#pragma unroll
    for (int r = 0; r < 16; ++r) acc[r] = 0.0f;

#pragma unroll
    for (int tap = 0; tap < 3; ++tap) {
        int jrow = cloc + tap + 1;                     // sp = s0 + cloc + tap - 1
        if (jrow > ROWS - 1) jrow = ROWS - 1;          // garbage cols only
        if ((tap == 0 && wpos == 0) || (tap == 2 && wpos == 55))
            jrow = ZROW;                               // boundary kill -> zero row
        const unsigned short* brow = &xs[jrow * CP + half * 8];
#pragma unroll
        for (int ks8 = 0; ks8 < 8; ++ks8) {
            bf16x8 b = *(const bf16x8*)(brow + ks8 * 16);
            const bf16x8 a = *(const bf16x8*)(af + (tap * 8 + ks8) * 512 + lane * 8);
            acc = __builtin_amdgcn_mfma_f32_32x32x16_bf16(a, b, acc, 0, 0, 0);
        }
    }

    // ---- store with roll: s -> (s+56) mod 3136 ; C/D: col=lane&31, row=(r&3)+8*(r>>2)+4*half
    if (cloc < ST && col < SP) {
        int sst = col + 56;
        if (sst >= SP) sst -= SP;
        float* op = out + (size_t)n * (OUTC * SP) + sst;
#pragma unroll
        for (int r = 0; r < 16; ++r) {
            int o = (r & 3) + 8 * (r >> 2) + 4 * half;
            __builtin_nontemporal_store(acc[r], op + o * SP);
        }
    }
}

extern "C" void kernel_launch(void* const* d_in, const int* in_sizes, int n_in,
                              void* d_out, int out_size, void* d_ws, size_t ws_size,
                              hipStream_t stream) {
    const float* x = (const float*)d_in[0];
    const float* w = (const float*)d_in[1];
    float* out = (float*)d_out;
    unsigned short* af = (unsigned short*)d_ws;        // 24*512 bf16 = 24 KB

    prep_w<<<dim3((OUTC * 384 + 255) / 256), dim3(256), 0, stream>>>(w, af);

    dim3 grid(NT, NB);                                  // 26 x 128
    conv_mfma<<<grid, dim3(THREADS), 0, stream>>>(x, af, out);
}

// Round 2
// 306.622 us; speedup vs baseline: 1.0095x; 1.0095x over previous
//
#include <hip/hip_runtime.h>
#include <hip/hip_bf16.h>

// out[n,o,(h+1)%56,w] = sum_{c,t} x[n,c,h,w+t-1] * W[o,c,t]   (W-pad 1, H-pad 0)
// Implicit GEMM on MFMA 32x32x16_bf16. K = tap*128 + c.
// LDS: x-window transposed; row j <-> sp = s0-2+j (even start -> dwordx2 staging),
// pitch 68 dwords (conflict-free b128 reads). Row 130 = zeros (boundary-kill row:
// kill is an address select, not 8 cndmasks). ST=126 -> 25 blocks, +3.6% over-read.

#define NB    128
#define CIN   128
#define SP    3136          // 56*56
#define HSP   1568          // SP/2 in float2 units
#define OUTC  32
#define ST    126           // s-cols stored per block
#define NT    25            // ceil(3136/126)
#define ROWS  130           // data rows j=0..129 <-> sp = s0-2+j
#define ZROW  130           // zero row for boundary kill
#define CP    136           // LDS row pitch in bf16 (68 dwords)
#define THREADS 256

typedef __attribute__((ext_vector_type(8)))  short bf16x8;   // 8 bf16 = 4 VGPRs
typedef __attribute__((ext_vector_type(16))) float f32x16;   // 32x32 accumulator

__device__ __forceinline__ unsigned short f2bf(float f) {    // RNE f32->bf16
    unsigned u = __float_as_uint(f);
    return (unsigned short)((u + 0x7FFFu + ((u >> 16) & 1u)) >> 16);
}

// packed RNE convert: compiler emits v_cvt_pk_bf16_f32 (1 op vs ~10 manual)
__device__ __forceinline__ unsigned cvt2(float a, float b) {
    union { __hip_bfloat162 h; unsigned u; } z;
    z.h = __float22bfloat162_rn(make_float2(a, b));
    return z.u;
}

// A-frag prep: af[ks][lane][8] bf16; frag elem j of lane = A[m=lane&31][k=ks*16+(lane>>5)*8+j]
__global__ void prep_w(const float* __restrict__ w, unsigned short* __restrict__ af) {
    int i = blockIdx.x * 256 + threadIdx.x;            // over 32 o x 384 k
    if (i >= OUTC * 384) return;
    int k = i % 384, o = i / 384;
    int tap = k / 128, c = k % 128;
    int kstep = k >> 4, klocal = k & 15;
    int lane  = ((klocal >> 3) << 5) + o;
    int j     = klocal & 7;
    af[kstep * 512 + lane * 8 + j] = f2bf(w[o * 384 + c * 3 + tap]);
}

__launch_bounds__(THREADS, 4)
__global__ void conv_mfma(const float* __restrict__ x,
                          const unsigned short* __restrict__ af,
                          float* __restrict__ out) {
    __shared__ unsigned short xs[(ROWS + 1) * CP];     // 35,632 B -> 4 blocks/CU

    const int n  = blockIdx.y;
    const int s0 = blockIdx.x * ST;
    const float* __restrict__ xn = x + (size_t)n * (CIN * SP);

    // ---- stage x[n, :, s0-2 .. s0+127] transposed into LDS as bf16 ----
    // pairs 0..63 via 4 full rounds (lane-consecutive -> 512B/instr dwordx2);
    // pair 64 (rows 128,129) + zero row via the 16-thread tail below.
#pragma unroll
    for (int it = 0; it < 4; ++it) {
        int i  = threadIdx.x + it * THREADS;           // 0..1023
        int p  = i & 63;                               // s-pair -> rows 2p, 2p+1
        int cg = i >> 6;                               // channel group of 8
        int s  = s0 - 2 + 2 * p;                       // even -> 8B-aligned float2
        s = s < 0 ? 0 : (s > SP - 2 ? SP - 2 : s);     // clamped; junk rows masked at use
        const float2* __restrict__ xp =
            (const float2*)xn + (size_t)(cg * 8) * HSP + (s >> 1);
        float2 v0 = xp[0 * HSP], v1 = xp[1 * HSP], v2 = xp[2 * HSP], v3 = xp[3 * HSP];
        float2 v4 = xp[4 * HSP], v5 = xp[5 * HSP], v6 = xp[6 * HSP], v7 = xp[7 * HSP];
        union { unsigned u[4]; bf16x8 v; } r0, r1;
        r0.u[0] = cvt2(v0.x, v1.x); r0.u[1] = cvt2(v2.x, v3.x);
        r0.u[2] = cvt2(v4.x, v5.x); r0.u[3] = cvt2(v6.x, v7.x);
        r1.u[0] = cvt2(v0.y, v1.y); r1.u[1] = cvt2(v2.y, v3.y);
        r1.u[2] = cvt2(v4.y, v5.y); r1.u[3] = cvt2(v6.y, v7.y);
        *(bf16x8*)&xs[(2 * p)     * CP + cg * 8] = r0.v;
        *(bf16x8*)&xs[(2 * p + 1) * CP + cg * 8] = r1.v;
    }
    if (threadIdx.x < 16) {
        // tail: pair 64 -> rows 128,129 (sp = s0+126, s0+127), one cg per thread
        int cg = threadIdx.x;
        int s  = s0 + 126;                             // even
        s = s > SP - 2 ? SP - 2 : s;                   // junk in last block, masked at use
        const float2* __restrict__ xp =
            (const float2*)xn + (size_t)(cg * 8) * HSP + (s >> 1);
        float2 v0 = xp[0 * HSP], v1 = xp[1 * HSP], v2 = xp[2 * HSP], v3 = xp[3 * HSP];
        float2 v4 = xp[4 * HSP], v5 = xp[5 * HSP], v6 = xp[6 * HSP], v7 = xp[7 * HSP];
        union { unsigned u[4]; bf16x8 v; } r0, r1;
        r0.u[0] = cvt2(v0.x, v1.x); r0.u[1] = cvt2(v2.x, v3.x);
        r0.u[2] = cvt2(v4.x, v5.x); r0.u[3] = cvt2(v6.x, v7.x);
        r1.u[0] = cvt2(v0.y, v1.y); r1.u[1] = cvt2(v2.y, v3.y);
        r1.u[2] = cvt2(v4.y, v5.y); r1.u[3] = cvt2(v6.y, v7.y);
        *(bf16x8*)&xs[128 * CP + cg * 8] = r0.v;
        *(bf16x8*)&xs[129 * CP + cg * 8] = r1.v;
        // zero the kill row (c = 0..127)
        bf16x8 z = {};
        *(bf16x8*)&xs[ZROW * CP + cg * 8] = z;
    }
    __syncthreads();

    const int lane = threadIdx.x & 63;
    const int wid  = threadIdx.x >> 6;                 // wave -> 32-col chunk
    const int cloc = wid * 32 + (lane & 31);           // local column (0..127; >=126 garbage)
    const int col  = s0 + cloc;                        // global s
    const int wpos = col % 56;
    const int half = lane >> 5;

    f32x16 acc;
#pragma unroll
    for (int r = 0; r < 16; ++r) acc[r] = 0.0f;

#pragma unroll
    for (int tap = 0; tap < 3; ++tap) {
        int jrow = cloc + tap + 1;                     // sp = s0 + cloc + tap - 1
        if (jrow > ROWS - 1) jrow = ROWS - 1;          // garbage cols only
        if ((tap == 0 && wpos == 0) || (tap == 2 && wpos == 55))
            jrow = ZROW;                               // boundary kill -> zero row
        const unsigned short* brow = &xs[jrow * CP + half * 8];
#pragma unroll
        for (int ks8 = 0; ks8 < 8; ++ks8) {
            bf16x8 b = *(const bf16x8*)(brow + ks8 * 16);
            const bf16x8 a = *(const bf16x8*)(af + (tap * 8 + ks8) * 512 + lane * 8);
            acc = __builtin_amdgcn_mfma_f32_32x32x16_bf16(a, b, acc, 0, 0, 0);
        }
    }

    // ---- store with roll: s -> (s+56) mod 3136 ; C/D: col=lane&31, row=(r&3)+8*(r>>2)+4*half
    if (cloc < ST && col < SP) {
        int sst = col + 56;
        if (sst >= SP) sst -= SP;
        float* op = out + (size_t)n * (OUTC * SP) + sst;
#pragma unroll
        for (int r = 0; r < 16; ++r) {
            int o = (r & 3) + 8 * (r >> 2) + 4 * half;
            op[o * SP] = acc[r];
        }
    }
}

extern "C" void kernel_launch(void* const* d_in, const int* in_sizes, int n_in,
                              void* d_out, int out_size, void* d_ws, size_t ws_size,
                              hipStream_t stream) {
    const float* x = (const float*)d_in[0];
    const float* w = (const float*)d_in[1];
    float* out = (float*)d_out;
    unsigned short* af = (unsigned short*)d_ws;        // 24*512 bf16 = 24 KB

    prep_w<<<dim3((OUTC * 384 + 255) / 256), dim3(256), 0, stream>>>(w, af);

    dim3 grid(NT, NB);                                  // 25 x 128
    conv_mfma<<<grid, dim3(THREADS), 0, stream>>>(x, af, out);
}